// Round 5
// baseline (177.376 us; speedup 1.0000x reference)
//
#include <hip/hip_runtime.h>
#include <hip/hip_bf16.h>

// Head: out[b,t,h] = softmax_causal( (x@Wq)(x@Wk)^T * 6^-0.5 ) @ (x@Wv)
// B=512 T=128 C=384 H=64. bf16 MFMA 16x16x32.
//
// V6: two-kernel split (empirical phase bisection + decoupling).
//  - qkv_gemm: V5's barrier-pipelined phase 1, then writes the swizzled
//    Q/K/Vt LDS image linearly to d_ws (coalesced b128). Pure streaming GEMM,
//    no attention coupling.
//  - attn: stages the 48KB image back with 6 linear global_load_lds units per
//    thread (one vmcnt(0) + one barrier), then V5's phase-2 verbatim.
//  - Intermediate 25.2MB lives in ws (L3-resident: written then read).
//  - If ws_size < 25.3MB, host falls back to the proven fused V5 kernel.

#define B_ 512
#define T_ 128
#define C_ 384
#define H_ 64

typedef __bf16 bf16;
typedef __attribute__((ext_vector_type(8))) __bf16 bf16x8;
typedef __attribute__((ext_vector_type(4))) __bf16 bf16x4;
typedef __attribute__((ext_vector_type(4))) float f32x4;

#define GLOAD_LDS16(g, l)                                                     \
    __builtin_amdgcn_global_load_lds(                                         \
        (const __attribute__((address_space(1))) void*)(g),                   \
        (__attribute__((address_space(3))) void*)(l), 16, 0, 0)

// ---------------- pre-kernel: W -> bf16 W^T in MFMA B-fragment order --------
__global__ void build_wt(const float* __restrict__ Wq, const float* __restrict__ Wk,
                         const float* __restrict__ Wv, bf16* __restrict__ Wt)
{
    int t = blockIdx.x * 256 + threadIdx.x;
    if (t >= 12 * 12 * 64) return;
    int lane = t & 63;
    int tn   = (t >> 6) % 12;
    int kc   = t / (12 * 64);
    int lm = lane & 15, quad = lane >> 4;
    int n = tn * 16 + lm;
    int j = n >> 6, h = n & 63;
    const float* Wp = (j == 0) ? Wq : (j == 1) ? Wk : Wv;
    int k0 = kc * 32 + quad * 8;
    bf16x8 v;
#pragma unroll
    for (int e = 0; e < 8; ++e) v[e] = (bf16)Wp[(k0 + e) * H_ + h];
    *(bf16x8*)&Wt[t * 8] = v;
}

// ======================= kernel A: QKV GEMM =======================
// LDS (57344B): k-loop 2 x 28KB buffers {x 16KB swizzled fp32, Wt 12KB linear};
// epilogue overwrites [0,49152) with Qs/Ks/Vts swizzled bf16, then linear
// writeback to qkv[b] (49152B per b).
__launch_bounds__(512, 4)
__global__ void qkv_gemm(const float* __restrict__ x,
                         const bf16* __restrict__ Wt,
                         bf16* __restrict__ qkv)
{
    __shared__ __align__(16) bf16 lds[28672];
    bf16* Qs  = lds;
    bf16* Ks  = lds + 8192;
    bf16* Vts = lds + 16384;

    const int tid  = threadIdx.x;
    const int w    = tid >> 6;
    const int lane = tid & 63;
    const int lm   = lane & 15;
    const int quad = lane >> 4;
    const int mg   = w >> 2;
    const int ng   = w & 3;
    const int b    = blockIdx.x;

    const float* xb = x + (size_t)b * (T_ * C_);

    f32x4 acc[4][3];
#pragma unroll
    for (int mf = 0; mf < 4; ++mf)
#pragma unroll
        for (int nf = 0; nf < 3; ++nf) acc[mf][nf] = (f32x4){0.f, 0.f, 0.f, 0.f};

    const int r0 = tid >> 3, r1 = (tid + 512) >> 3;
    const float* gx0 = xb + (size_t)r0 * C_ + (((tid & 7) ^ (r0 & 7)) * 4);
    const float* gx1 = xb + (size_t)r1 * C_ + (((tid & 7) ^ (r1 & 7)) * 4);
    char* lx0 = (char*)lds + w * 1024;
    char* lx1 = (char*)lds + 8192 + w * 1024;
    const char* gwt = (const char*)Wt;
    char* lw0 = (char*)lds + 16384 + w * 1024;
    char* lw1 = (char*)lds + 16384 + 8192 + w * 1024;

    auto STAGE = [&](int kc) {
        int bo = (kc & 1) * 28672;
        GLOAD_LDS16(gx0 + kc * 32, lx0 + bo);
        GLOAD_LDS16(gx1 + kc * 32, lx1 + bo);
        GLOAD_LDS16(gwt + (size_t)kc * 12288 + tid * 16, lw0 + bo);
        if (w < 4)
            GLOAD_LDS16(gwt + (size_t)kc * 12288 + 8192 + tid * 16, lw1 + bo);
    };

    STAGE(0);
    asm volatile("s_waitcnt vmcnt(0)" ::: "memory");
    __builtin_amdgcn_s_barrier();

#pragma unroll
    for (int kc = 0; kc < 12; ++kc) {
        if (kc < 11) STAGE(kc + 1);

        const float* xc = (const float*)((const char*)lds + (kc & 1) * 28672);
        const bf16*  wc = (const bf16*)((const char*)lds + (kc & 1) * 28672 + 16384);

        bf16x8 afr[4];
#pragma unroll
        for (int mf = 0; mf < 4; ++mf) {
            int row = 64 * mg + 16 * mf + lm;
            int p0 = (2 * quad) ^ (row & 7);
            int p1 = (2 * quad + 1) ^ (row & 7);
            f32x4 va = *(const f32x4*)(xc + row * 32 + p0 * 4);
            f32x4 vb = *(const f32x4*)(xc + row * 32 + p1 * 4);
            afr[mf] = (bf16x8){(bf16)va[0], (bf16)va[1], (bf16)va[2], (bf16)va[3],
                               (bf16)vb[0], (bf16)vb[1], (bf16)vb[2], (bf16)vb[3]};
        }
#pragma unroll
        for (int nf = 0; nf < 3; ++nf) {
            bf16x8 bfr = *(const bf16x8*)(wc + (3 * ng + nf) * 512 + lane * 8);
#pragma unroll
            for (int mf = 0; mf < 4; ++mf)
                acc[mf][nf] =
                    __builtin_amdgcn_mfma_f32_16x16x32_bf16(afr[mf], bfr, acc[mf][nf], 0, 0, 0);
        }

        if (kc < 11) {
            asm volatile("s_waitcnt vmcnt(0)" ::: "memory");
            __builtin_amdgcn_s_barrier();
        }
    }
    __syncthreads();   // staging dies; write Q/K/Vt image

#pragma unroll
    for (int mf = 0; mf < 4; ++mf) {
#pragma unroll
        for (int nf = 0; nf < 3; ++nf) {
            int tn = 3 * ng + nf;
            int gn = 16 * tn + lm;
            int j = gn >> 6, h = gn & 63;
            int m0 = 64 * mg + 16 * mf + quad * 4;
            if (j == 2) {
                bf16x4 v4 = {(bf16)acc[mf][nf][0], (bf16)acc[mf][nf][1],
                             (bf16)acc[mf][nf][2], (bf16)acc[mf][nf][3]};
                int pc = (m0 & 7) | ((((m0 >> 3) ^ (h & 15)) & 15) << 3);
                *(bf16x4*)&Vts[h * 128 + pc] = v4;
            } else {
                bf16* dst = (j == 0) ? Qs : Ks;
#pragma unroll
                for (int r = 0; r < 4; ++r) {
                    int m = m0 + r;
                    int pc = (h & 7) | ((((h >> 3) ^ (m & 7)) & 7) << 3);
                    dst[m * 64 + pc] = (bf16)acc[mf][nf][r];
                }
            }
        }
    }
    __syncthreads();

    // linear coalesced writeback of the 48KB image
    char* dst = (char*)qkv + (size_t)b * 49152;
    const char* ldsb = (const char*)lds;
#pragma unroll
    for (int u = 0; u < 6; ++u) {
        int off = (u * 512 + tid) * 16;
        *(float4*)(dst + off) = *(const float4*)(ldsb + off);
    }
}

// ======================= kernel B: attention =======================
// LDS 49152B: Qs [0,8192) elems, Ks [8192,16384), Vts [16384,24576),
// Ps aliases [0,16384). Staged as a verbatim linear copy of qkv[b].
__launch_bounds__(512, 4)
__global__ void attn(const bf16* __restrict__ qkv, float* __restrict__ out)
{
    __shared__ __align__(16) bf16 lds[24576];
    bf16* Qs  = lds;
    bf16* Ks  = lds + 8192;
    bf16* Vts = lds + 16384;
    bf16* Ps  = lds;

    const int tid  = threadIdx.x;
    const int w    = tid >> 6;
    const int lane = tid & 63;
    const int lm   = lane & 15;
    const int quad = lane >> 4;
    const int b    = blockIdx.x;

    // stage 48KB linearly: 6 x 16B units per thread, wave-uniform LDS base
    const char* src = (const char*)qkv + (size_t)b * 49152;
    char* ldsb = (char*)lds + w * 1024;   // + lane*16 added by HW
#pragma unroll
    for (int u = 0; u < 6; ++u)
        GLOAD_LDS16(src + (u * 512 + tid) * 16, ldsb + u * 8192);
    asm volatile("s_waitcnt vmcnt(0)" ::: "memory");
    __syncthreads();

    const float SCALE = 0.40824829046386307f;  // 6^-0.5
    const int tm = w;
    const int mrow = 16 * tm + lm;

    f32x4 sacc[8];
#pragma unroll
    for (int t = 0; t < 8; ++t) sacc[t] = (f32x4){0.f, 0.f, 0.f, 0.f};

    bf16x8 qa[2];
#pragma unroll
    for (int ks = 0; ks < 2; ++ks) {
        int phys = ((ks * 4 + quad) ^ (mrow & 7)) & 7;
        qa[ks] = *(const bf16x8*)&Qs[mrow * 64 + phys * 8];
    }
#pragma unroll
    for (int tn = 0; tn < 8; ++tn) {
        if (tn <= tm) {
            int nrow = 16 * tn + lm;
#pragma unroll
            for (int ks = 0; ks < 2; ++ks) {
                int phys = ((ks * 4 + quad) ^ (nrow & 7)) & 7;
                bf16x8 kb = *(const bf16x8*)&Ks[nrow * 64 + phys * 8];
                sacc[tn] =
                    __builtin_amdgcn_mfma_f32_16x16x32_bf16(qa[ks], kb, sacc[tn], 0, 0, 0);
            }
        }
    }

#pragma unroll
    for (int r = 0; r < 4; ++r) {
        int m = 16 * tm + quad * 4 + r;
        float mx = -1e30f;
#pragma unroll
        for (int tn = 0; tn < 8; ++tn) {
            if (tn <= tm) {
                int n = 16 * tn + lm;
                float v = (n <= m) ? sacc[tn][r] * SCALE : -1e30f;
                sacc[tn][r] = v;
                mx = fmaxf(mx, v);
            }
        }
#pragma unroll
        for (int off = 1; off < 16; off <<= 1) mx = fmaxf(mx, __shfl_xor(mx, off, 16));
        float sum = 0.f;
#pragma unroll
        for (int tn = 0; tn < 8; ++tn) {
            if (tn <= tm) {
                float e = __expf(sacc[tn][r] - mx);
                sacc[tn][r] = e;
                sum += e;
            }
        }
#pragma unroll
        for (int off = 1; off < 16; off <<= 1) sum += __shfl_xor(sum, off, 16);
        float inv = 1.f / sum;
#pragma unroll
        for (int tn = 0; tn < 8; ++tn) {
            if (tn <= tm) sacc[tn][r] *= inv;
        }
    }

    __syncthreads();  // done reading Qs/Ks; Ps aliases them

#pragma unroll
    for (int tn = 0; tn < 8; ++tn) {
        if (tn <= tm) {
            int n = 16 * tn + lm;
#pragma unroll
            for (int r = 0; r < 4; ++r) {
                int m = 16 * tm + quad * 4 + r;
                int pc = (n & 7) | ((((n >> 3) ^ (m & 15)) & 15) << 3);
                Ps[m * 128 + pc] = (bf16)sacc[tn][r];
            }
        }
    }
    if ((tm & 1) == 0) {
        int m = 16 * tm + lm;
        int c0 = 16 * (tm + 1) + quad * 4;
        int pc = (c0 & 7) | ((((c0 >> 3) ^ (m & 15)) & 15) << 3);
        *(bf16x4*)&Ps[m * 128 + pc] =
            (bf16x4){(bf16)0.f, (bf16)0.f, (bf16)0.f, (bf16)0.f};
    }

    f32x4 oacc[4];
#pragma unroll
    for (int t = 0; t < 4; ++t) oacc[t] = (f32x4){0.f, 0.f, 0.f, 0.f};

    const int nks = (tm + 2) >> 1;
    for (int ks = 0; ks < nks; ++ks) {
        int unit = ks * 4 + quad;
        int phys = (unit ^ (mrow & 15)) & 15;
        bf16x8 pa = *(const bf16x8*)&Ps[mrow * 128 + phys * 8];
#pragma unroll
        for (int th = 0; th < 4; ++th) {
            int hrow = 16 * th + lm;
            int ph2 = (unit ^ (hrow & 15)) & 15;
            bf16x8 vb = *(const bf16x8*)&Vts[hrow * 128 + ph2 * 8];
            oacc[th] =
                __builtin_amdgcn_mfma_f32_16x16x32_bf16(pa, vb, oacc[th], 0, 0, 0);
        }
    }

    float* ob = out + (size_t)b * (T_ * H_);
#pragma unroll
    for (int th = 0; th < 4; ++th) {
        int h = 16 * th + lm;
#pragma unroll
        for (int r = 0; r < 4; ++r) {
            int m = 16 * tm + quad * 4 + r;
            ob[m * 64 + h] = oacc[th][r];
        }
    }
}

// ======================= fallback: fused V5 (proven) =======================
__launch_bounds__(512, 4)
__global__ void head_fused(const float* __restrict__ x,
                           const bf16* __restrict__ Wt,
                           float* __restrict__ out)
{
    __shared__ __align__(16) bf16 lds[28672];
    bf16* Qs  = lds;
    bf16* Ks  = lds + 8192;
    bf16* Vts = lds + 16384;
    bf16* Ps  = lds;

    const int tid  = threadIdx.x;
    const int w    = tid >> 6;
    const int lane = tid & 63;
    const int lm   = lane & 15;
    const int quad = lane >> 4;
    const int mg   = w >> 2;
    const int ng   = w & 3;
    const int b    = blockIdx.x;

    const float* xb = x + (size_t)b * (T_ * C_);

    f32x4 acc[4][3];
#pragma unroll
    for (int mf = 0; mf < 4; ++mf)
#pragma unroll
        for (int nf = 0; nf < 3; ++nf) acc[mf][nf] = (f32x4){0.f, 0.f, 0.f, 0.f};

    const int r0 = tid >> 3, r1 = (tid + 512) >> 3;
    const float* gx0 = xb + (size_t)r0 * C_ + (((tid & 7) ^ (r0 & 7)) * 4);
    const float* gx1 = xb + (size_t)r1 * C_ + (((tid & 7) ^ (r1 & 7)) * 4);
    char* lx0 = (char*)lds + w * 1024;
    char* lx1 = (char*)lds + 8192 + w * 1024;
    const char* gwt = (const char*)Wt;
    char* lw0 = (char*)lds + 16384 + w * 1024;
    char* lw1 = (char*)lds + 16384 + 8192 + w * 1024;

    auto STAGE = [&](int kc) {
        int bo = (kc & 1) * 28672;
        GLOAD_LDS16(gx0 + kc * 32, lx0 + bo);
        GLOAD_LDS16(gx1 + kc * 32, lx1 + bo);
        GLOAD_LDS16(gwt + (size_t)kc * 12288 + tid * 16, lw0 + bo);
        if (w < 4)
            GLOAD_LDS16(gwt + (size_t)kc * 12288 + 8192 + tid * 16, lw1 + bo);
    };

    STAGE(0);
    asm volatile("s_waitcnt vmcnt(0)" ::: "memory");
    __builtin_amdgcn_s_barrier();

#pragma unroll
    for (int kc = 0; kc < 12; ++kc) {
        if (kc < 11) STAGE(kc + 1);

        const float* xc = (const float*)((const char*)lds + (kc & 1) * 28672);
        const bf16*  wc = (const bf16*)((const char*)lds + (kc & 1) * 28672 + 16384);

        bf16x8 afr[4];
#pragma unroll
        for (int mf = 0; mf < 4; ++mf) {
            int row = 64 * mg + 16 * mf + lm;
            int p0 = (2 * quad) ^ (row & 7);
            int p1 = (2 * quad + 1) ^ (row & 7);
            f32x4 va = *(const f32x4*)(xc + row * 32 + p0 * 4);
            f32x4 vb = *(const f32x4*)(xc + row * 32 + p1 * 4);
            afr[mf] = (bf16x8){(bf16)va[0], (bf16)va[1], (bf16)va[2], (bf16)va[3],
                               (bf16)vb[0], (bf16)vb[1], (bf16)vb[2], (bf16)vb[3]};
        }
#pragma unroll
        for (int nf = 0; nf < 3; ++nf) {
            bf16x8 bfr = *(const bf16x8*)(wc + (3 * ng + nf) * 512 + lane * 8);
#pragma unroll
            for (int mf = 0; mf < 4; ++mf)
                acc[mf][nf] =
                    __builtin_amdgcn_mfma_f32_16x16x32_bf16(afr[mf], bfr, acc[mf][nf], 0, 0, 0);
        }

        if (kc < 11) {
            asm volatile("s_waitcnt vmcnt(0)" ::: "memory");
            __builtin_amdgcn_s_barrier();
        }
    }
    __syncthreads();

#pragma unroll
    for (int mf = 0; mf < 4; ++mf) {
#pragma unroll
        for (int nf = 0; nf < 3; ++nf) {
            int tn = 3 * ng + nf;
            int gn = 16 * tn + lm;
            int j = gn >> 6, h = gn & 63;
            int m0 = 64 * mg + 16 * mf + quad * 4;
            if (j == 2) {
                bf16x4 v4 = {(bf16)acc[mf][nf][0], (bf16)acc[mf][nf][1],
                             (bf16)acc[mf][nf][2], (bf16)acc[mf][nf][3]};
                int pc = (m0 & 7) | ((((m0 >> 3) ^ (h & 15)) & 15) << 3);
                *(bf16x4*)&Vts[h * 128 + pc] = v4;
            } else {
                bf16* dst = (j == 0) ? Qs : Ks;
#pragma unroll
                for (int r = 0; r < 4; ++r) {
                    int m = m0 + r;
                    int pc = (h & 7) | ((((h >> 3) ^ (m & 7)) & 7) << 3);
                    dst[m * 64 + pc] = (bf16)acc[mf][nf][r];
                }
            }
        }
    }
    __syncthreads();

    const float SCALE = 0.40824829046386307f;
    const int tm = w;
    const int mrow = 16 * tm + lm;

    f32x4 sacc[8];
#pragma unroll
    for (int t = 0; t < 8; ++t) sacc[t] = (f32x4){0.f, 0.f, 0.f, 0.f};

    bf16x8 qa[2];
#pragma unroll
    for (int ks = 0; ks < 2; ++ks) {
        int phys = ((ks * 4 + quad) ^ (mrow & 7)) & 7;
        qa[ks] = *(const bf16x8*)&Qs[mrow * 64 + phys * 8];
    }
#pragma unroll
    for (int tn = 0; tn < 8; ++tn) {
        if (tn <= tm) {
            int nrow = 16 * tn + lm;
#pragma unroll
            for (int ks = 0; ks < 2; ++ks) {
                int phys = ((ks * 4 + quad) ^ (nrow & 7)) & 7;
                bf16x8 kb = *(const bf16x8*)&Ks[nrow * 64 + phys * 8];
                sacc[tn] =
                    __builtin_amdgcn_mfma_f32_16x16x32_bf16(qa[ks], kb, sacc[tn], 0, 0, 0);
            }
        }
    }

#pragma unroll
    for (int r = 0; r < 4; ++r) {
        int m = 16 * tm + quad * 4 + r;
        float mx = -1e30f;
#pragma unroll
        for (int tn = 0; tn < 8; ++tn) {
            if (tn <= tm) {
                int n = 16 * tn + lm;
                float v = (n <= m) ? sacc[tn][r] * SCALE : -1e30f;
                sacc[tn][r] = v;
                mx = fmaxf(mx, v);
            }
        }
#pragma unroll
        for (int off = 1; off < 16; off <<= 1) mx = fmaxf(mx, __shfl_xor(mx, off, 16));
        float sum = 0.f;
#pragma unroll
        for (int tn = 0; tn < 8; ++tn) {
            if (tn <= tm) {
                float e = __expf(sacc[tn][r] - mx);
                sacc[tn][r] = e;
                sum += e;
            }
        }
#pragma unroll
        for (int off = 1; off < 16; off <<= 1) sum += __shfl_xor(sum, off, 16);
        float inv = 1.f / sum;
#pragma unroll
        for (int tn = 0; tn < 8; ++tn) {
            if (tn <= tm) sacc[tn][r] *= inv;
        }
    }

    __syncthreads();

#pragma unroll
    for (int tn = 0; tn < 8; ++tn) {
        if (tn <= tm) {
            int n = 16 * tn + lm;
#pragma unroll
            for (int r = 0; r < 4; ++r) {
                int m = 16 * tm + quad * 4 + r;
                int pc = (n & 7) | ((((n >> 3) ^ (m & 15)) & 15) << 3);
                Ps[m * 128 + pc] = (bf16)sacc[tn][r];
            }
        }
    }
    if ((tm & 1) == 0) {
        int m = 16 * tm + lm;
        int c0 = 16 * (tm + 1) + quad * 4;
        int pc = (c0 & 7) | ((((c0 >> 3) ^ (m & 15)) & 15) << 3);
        *(bf16x4*)&Ps[m * 128 + pc] =
            (bf16x4){(bf16)0.f, (bf16)0.f, (bf16)0.f, (bf16)0.f};
    }

    f32x4 oacc[4];
#pragma unroll
    for (int t = 0; t < 4; ++t) oacc[t] = (f32x4){0.f, 0.f, 0.f, 0.f};

    const int nks = (tm + 2) >> 1;
    for (int ks = 0; ks < nks; ++ks) {
        int unit = ks * 4 + quad;
        int phys = (unit ^ (mrow & 15)) & 15;
        bf16x8 pa = *(const bf16x8*)&Ps[mrow * 128 + phys * 8];
#pragma unroll
        for (int th = 0; th < 4; ++th) {
            int hrow = 16 * th + lm;
            int ph2 = (unit ^ (hrow & 15)) & 15;
            bf16x8 vb = *(const bf16x8*)&Vts[hrow * 128 + ph2 * 8];
            oacc[th] =
                __builtin_amdgcn_mfma_f32_16x16x32_bf16(pa, vb, oacc[th], 0, 0, 0);
        }
    }

    float* ob = out + (size_t)b * (T_ * H_);
#pragma unroll
    for (int th = 0; th < 4; ++th) {
        int h = 16 * th + lm;
#pragma unroll
        for (int r = 0; r < 4; ++r) {
            int m = 16 * tm + quad * 4 + r;
            ob[m * 64 + h] = oacc[th][r];
        }
    }
}

extern "C" void kernel_launch(void* const* d_in, const int* in_sizes, int n_in,
                              void* d_out, int out_size, void* d_ws, size_t ws_size,
                              hipStream_t stream) {
    const float* x  = (const float*)d_in[0];
    const float* Wq = (const float*)d_in[1];
    const float* Wk = (const float*)d_in[2];
    const float* Wv = (const float*)d_in[3];
    float* o = (float*)d_out;
    bf16* Wt = (bf16*)d_ws;                       // 147456 B
    const size_t WT_BYTES  = 147456;
    const size_t QKV_BYTES = (size_t)B_ * 49152;  // 25165824 B

    build_wt<<<dim3(36), dim3(256), 0, stream>>>(Wq, Wk, Wv, Wt);
    if (ws_size >= WT_BYTES + QKV_BYTES) {
        bf16* qkv = (bf16*)((char*)d_ws + WT_BYTES);
        qkv_gemm<<<dim3(B_), dim3(512), 0, stream>>>(x, Wt, qkv);
        attn<<<dim3(B_), dim3(512), 0, stream>>>(qkv, o);
    } else {
        head_fused<<<dim3(B_), dim3(512), 0, stream>>>(x, Wt, o);
    }
}

// Round 7
// 172.351 us; speedup vs baseline: 1.0292x; 1.0292x over previous
//
#include <hip/hip_runtime.h>
#include <hip/hip_bf16.h>

// Head: out[b,t,h] = softmax_causal( (x@Wq)(x@Wk)^T * 6^-0.5 ) @ (x@Wv)
// B=512 T=128 C=384 H=64. One block per b, bf16 MFMA 16x16x32.
//
// V7 (resubmit after infra failure; source audited, unchanged):
// deep pipeline (T3/T4) — counted vmcnt, never drain in main loop.
//  - V5 post-mortem: 2 buffers + vmcnt(0)/iter = pipeline depth 1; all 512
//    blocks in lockstep wait full HBM latency+queueing every chunk (m233
//    "2-phase stall"). V6 split proved no single phase dominates -> the
//    per-iteration drain is the spread-out cost.
//  - 4 buffers x 28KB = 112KB LDS, 3 chunks in flight steady-state,
//    s_waitcnt vmcnt(2L) at iteration bottoms (L=4 loads/thread for waves
//    0-3, 3 for waves 4-7; tail steps L -> 0). lgkmcnt(0) folded in so no
//    wave crosses a barrier with pending ds_reads (DMA overwrite safety).
//  - 112KB -> 1 block/CU, 8 waves. V3 proved occupancy isn't the lever here;
//    depth is. Attention region (48KB) aliases buffers 0-1 after the loop.
//  - k-loop FIFO stays pure global_load_lds (V4's poisoning lesson).

#define B_ 512
#define T_ 128
#define C_ 384
#define H_ 64

typedef __bf16 bf16;
typedef __attribute__((ext_vector_type(8))) __bf16 bf16x8;
typedef __attribute__((ext_vector_type(4))) __bf16 bf16x4;
typedef __attribute__((ext_vector_type(4))) float f32x4;

#define GLOAD_LDS16(g, l)                                                     \
    __builtin_amdgcn_global_load_lds(                                         \
        (const __attribute__((address_space(1))) void*)(g),                   \
        (__attribute__((address_space(3))) void*)(l), 16, 0, 0)

// ---------------- pre-kernel: W -> bf16 W^T in MFMA B-fragment order --------
// Wt[((kc*12 + tn)*64 + lane)*8 + e] = Wsel[(kc*32 + quad*8 + e)*64 + h]
__global__ void build_wt(const float* __restrict__ Wq, const float* __restrict__ Wk,
                         const float* __restrict__ Wv, bf16* __restrict__ Wt)
{
    int t = blockIdx.x * 256 + threadIdx.x;
    if (t >= 12 * 12 * 64) return;
    int lane = t & 63;
    int tn   = (t >> 6) % 12;
    int kc   = t / (12 * 64);
    int lm = lane & 15, quad = lane >> 4;
    int n = tn * 16 + lm;
    int j = n >> 6, h = n & 63;
    const float* Wp = (j == 0) ? Wq : (j == 1) ? Wk : Wv;
    int k0 = kc * 32 + quad * 8;
    bf16x8 v;
#pragma unroll
    for (int e = 0; e < 8; ++e) v[e] = (bf16)Wp[(k0 + e) * H_ + h];
    *(bf16x8*)&Wt[t * 8] = v;
}

// LDS (114688 bytes -> 1 block/CU):
//  k-loop, buffer p in {0,1,2,3} at byte p*28672:
//    x  [+0, +16384)     : 128 rows x 8 swizzled 16B units (fp32)
//    Wt [+16384, +28672) : linear copy of 12KB Wt chunk
//  after k-loop (aliases buffers 0-1):
//    Qs [0,8192) elems, Ks [8192,16384), Vts [16384,24576), Ps aliases [0,16384)

__launch_bounds__(512, 2)
__global__ void head_fused(const float* __restrict__ x,
                           const bf16* __restrict__ Wt,
                           float* __restrict__ out)
{
    __shared__ __align__(16) bf16 lds[57344];   // 114688 B
    bf16* Qs  = lds;
    bf16* Ks  = lds + 8192;
    bf16* Vts = lds + 16384;
    bf16* Ps  = lds;

    const int tid  = threadIdx.x;
    const int w    = tid >> 6;     // wave 0..7
    const int lane = tid & 63;
    const int lm   = lane & 15;
    const int quad = lane >> 4;
    const int mg   = w >> 2;       // m-group 0..1 (64 rows each)
    const int ng   = w & 3;        // n-group 0..3 (3 tiles each)
    const int b    = blockIdx.x;

    const float* xb = x + (size_t)b * (T_ * C_);

    // ================= Phase 1: QKV = x[b] @ [Wq|Wk|Wv] =================
    f32x4 acc[4][3];
#pragma unroll
    for (int mf = 0; mf < 4; ++mf)
#pragma unroll
        for (int nf = 0; nf < 3; ++nf) acc[mf][nf] = (f32x4){0.f, 0.f, 0.f, 0.f};

    // ---- staging addresses ----
    // x: unit u in [0,1024) holds global (row=u>>3, srcunit=(u&7)^(row&7));
    //    thread t stages units t and t+512 (LDS dest linear = wave base + lane*16).
    const int r0 = tid >> 3, r1 = (tid + 512) >> 3;
    const float* gx0 = xb + (size_t)r0 * C_ + (((tid & 7) ^ (r0 & 7)) * 4);
    const float* gx1 = xb + (size_t)r1 * C_ + (((tid & 7) ^ (r1 & 7)) * 4);
    char* lx0 = (char*)lds + w * 1024;
    char* lx1 = (char*)lds + 8192 + w * 1024;
    // Wt: linear 12KB copy; thread t stages unit t; waves 0..3 also unit 512+t.
    const char* gwt = (const char*)Wt;
    char* lw0 = (char*)lds + 16384 + w * 1024;
    char* lw1 = (char*)lds + 16384 + 8192 + w * 1024;

    // loads/thread/chunk: waves 0-3: L=4, waves 4-7: L=3 (wave-uniform)
    auto STAGE = [&](int kc) {
        int bo = (kc & 3) * 28672;
        GLOAD_LDS16(gx0 + kc * 32, lx0 + bo);
        GLOAD_LDS16(gx1 + kc * 32, lx1 + bo);
        GLOAD_LDS16(gwt + (size_t)kc * 12288 + tid * 16, lw0 + bo);
        if (w < 4)
            GLOAD_LDS16(gwt + (size_t)kc * 12288 + 8192 + tid * 16, lw1 + bo);
    };

    STAGE(0);
    STAGE(1);
    STAGE(2);
    // chunk 0 done; chunks 1,2 stay in flight (allow 2L newest)
    if (w < 4) asm volatile("s_waitcnt vmcnt(8)" ::: "memory");
    else       asm volatile("s_waitcnt vmcnt(6)" ::: "memory");
    __builtin_amdgcn_s_barrier();

#pragma unroll
    for (int kc = 0; kc < 12; ++kc) {
        // buf (kc+3)&3 == (kc-1)&3: all waves finished reading it at the
        // barrier that ended iter kc-1.
        if (kc + 3 < 12) STAGE(kc + 3);

        const float* xc = (const float*)((const char*)lds + (kc & 3) * 28672);
        const bf16*  wc = (const bf16*)((const char*)lds + (kc & 3) * 28672 + 16384);

        bf16x8 afr[4];
#pragma unroll
        for (int mf = 0; mf < 4; ++mf) {
            int row = 64 * mg + 16 * mf + lm;
            int p0 = (2 * quad) ^ (row & 7);
            int p1 = (2 * quad + 1) ^ (row & 7);
            f32x4 va = *(const f32x4*)(xc + row * 32 + p0 * 4);
            f32x4 vb = *(const f32x4*)(xc + row * 32 + p1 * 4);
            afr[mf] = (bf16x8){(bf16)va[0], (bf16)va[1], (bf16)va[2], (bf16)va[3],
                               (bf16)vb[0], (bf16)vb[1], (bf16)vb[2], (bf16)vb[3]};
        }
#pragma unroll
        for (int nf = 0; nf < 3; ++nf) {
            bf16x8 bfr = *(const bf16x8*)(wc + (3 * ng + nf) * 512 + lane * 8);
#pragma unroll
            for (int mf = 0; mf < 4; ++mf)
                acc[mf][nf] =
                    __builtin_amdgcn_mfma_f32_16x16x32_bf16(afr[mf], bfr, acc[mf][nf], 0, 0, 0);
        }

        // ensure chunk kc+1 landed; keep younger chunks in flight.
        // outstanding: kc<=8 -> {kc+1,kc+2,kc+3}; kc==9 -> {10,11}; kc==10 -> {11}.
        // lgkmcnt(0): no wave crosses the barrier with pending ds_reads, so
        // the next iter's DMA into the retired buffer can never race them.
        if (kc <= 8) {
            if (w < 4) asm volatile("s_waitcnt vmcnt(8) lgkmcnt(0)" ::: "memory");
            else       asm volatile("s_waitcnt vmcnt(6) lgkmcnt(0)" ::: "memory");
            __builtin_amdgcn_s_barrier();
        } else if (kc == 9) {
            if (w < 4) asm volatile("s_waitcnt vmcnt(4) lgkmcnt(0)" ::: "memory");
            else       asm volatile("s_waitcnt vmcnt(3) lgkmcnt(0)" ::: "memory");
            __builtin_amdgcn_s_barrier();
        } else if (kc == 10) {
            asm volatile("s_waitcnt vmcnt(0) lgkmcnt(0)" ::: "memory");
            __builtin_amdgcn_s_barrier();
        }
    }
    __syncthreads();   // full drain; staging dies, Q/K/Vt region becomes live

    // epilogue: Q,K row-major [t][h]; V transposed [h][t]; all swizzled bf16
#pragma unroll
    for (int mf = 0; mf < 4; ++mf) {
#pragma unroll
        for (int nf = 0; nf < 3; ++nf) {
            int tn = 3 * ng + nf;
            int gn = 16 * tn + lm;
            int j = gn >> 6, h = gn & 63;
            int m0 = 64 * mg + 16 * mf + quad * 4;
            if (j == 2) {
                bf16x4 v4 = {(bf16)acc[mf][nf][0], (bf16)acc[mf][nf][1],
                             (bf16)acc[mf][nf][2], (bf16)acc[mf][nf][3]};
                int pc = (m0 & 7) | ((((m0 >> 3) ^ (h & 15)) & 15) << 3);
                *(bf16x4*)&Vts[h * 128 + pc] = v4;
            } else {
                bf16* dst = (j == 0) ? Qs : Ks;
#pragma unroll
                for (int r = 0; r < 4; ++r) {
                    int m = m0 + r;
                    int pc = (h & 7) | ((((h >> 3) ^ (m & 7)) & 7) << 3);
                    dst[m * 64 + pc] = (bf16)acc[mf][nf][r];
                }
            }
        }
    }
    __syncthreads();

    // ================= Phase 2: attention =================
    const float SCALE = 0.40824829046386307f;  // 6^-0.5
    const int tm = w;
    const int mrow = 16 * tm + lm;

    f32x4 sacc[8];
#pragma unroll
    for (int t = 0; t < 8; ++t) sacc[t] = (f32x4){0.f, 0.f, 0.f, 0.f};

    bf16x8 qa[2];
#pragma unroll
    for (int ks = 0; ks < 2; ++ks) {
        int phys = ((ks * 4 + quad) ^ (mrow & 7)) & 7;
        qa[ks] = *(const bf16x8*)&Qs[mrow * 64 + phys * 8];
    }
#pragma unroll
    for (int tn = 0; tn < 8; ++tn) {
        if (tn <= tm) {
            int nrow = 16 * tn + lm;
#pragma unroll
            for (int ks = 0; ks < 2; ++ks) {
                int phys = ((ks * 4 + quad) ^ (nrow & 7)) & 7;
                bf16x8 kb = *(const bf16x8*)&Ks[nrow * 64 + phys * 8];
                sacc[tn] =
                    __builtin_amdgcn_mfma_f32_16x16x32_bf16(qa[ks], kb, sacc[tn], 0, 0, 0);
            }
        }
    }

    // softmax, fully in registers
#pragma unroll
    for (int r = 0; r < 4; ++r) {
        int m = 16 * tm + quad * 4 + r;
        float mx = -1e30f;
#pragma unroll
        for (int tn = 0; tn < 8; ++tn) {
            if (tn <= tm) {
                int n = 16 * tn + lm;
                float v = (n <= m) ? sacc[tn][r] * SCALE : -1e30f;
                sacc[tn][r] = v;
                mx = fmaxf(mx, v);
            }
        }
#pragma unroll
        for (int off = 1; off < 16; off <<= 1) mx = fmaxf(mx, __shfl_xor(mx, off, 16));
        float sum = 0.f;
#pragma unroll
        for (int tn = 0; tn < 8; ++tn) {
            if (tn <= tm) {
                float e = __expf(sacc[tn][r] - mx);
                sacc[tn][r] = e;
                sum += e;
            }
        }
#pragma unroll
        for (int off = 1; off < 16; off <<= 1) sum += __shfl_xor(sum, off, 16);
        float inv = 1.f / sum;
#pragma unroll
        for (int tn = 0; tn < 8; ++tn) {
            if (tn <= tm) sacc[tn][r] *= inv;
        }
    }

    __syncthreads();  // everyone done reading Qs/Ks; Ps aliases them

    // write P (bf16, swizzled); each wave writes only its own rows
#pragma unroll
    for (int tn = 0; tn < 8; ++tn) {
        if (tn <= tm) {
            int n = 16 * tn + lm;
#pragma unroll
            for (int r = 0; r < 4; ++r) {
                int m = 16 * tm + quad * 4 + r;
                int pc = (n & 7) | ((((n >> 3) ^ (m & 15)) & 15) << 3);
                Ps[m * 128 + pc] = (bf16)sacc[tn][r];
            }
        }
    }
    if ((tm & 1) == 0) {  // zero the half-covered k-tile (tm even)
        int m = 16 * tm + lm;
        int c0 = 16 * (tm + 1) + quad * 4;
        int pc = (c0 & 7) | ((((c0 >> 3) ^ (m & 15)) & 15) << 3);
        *(bf16x4*)&Ps[m * 128 + pc] =
            (bf16x4){(bf16)0.f, (bf16)0.f, (bf16)0.f, (bf16)0.f};
    }

    // O = P @ V  (reads only own P rows -> no barrier needed before PV)
    f32x4 oacc[4];
#pragma unroll
    for (int t = 0; t < 4; ++t) oacc[t] = (f32x4){0.f, 0.f, 0.f, 0.f};

    const int nks = (tm + 2) >> 1;
    for (int ks = 0; ks < nks; ++ks) {  // wave-uniform bound
        int unit = ks * 4 + quad;
        int phys = (unit ^ (mrow & 15)) & 15;
        bf16x8 pa = *(const bf16x8*)&Ps[mrow * 128 + phys * 8];
#pragma unroll
        for (int th = 0; th < 4; ++th) {
            int hrow = 16 * th + lm;
            int ph2 = (unit ^ (hrow & 15)) & 15;
            bf16x8 vb = *(const bf16x8*)&Vts[hrow * 128 + ph2 * 8];
            oacc[th] =
                __builtin_amdgcn_mfma_f32_16x16x32_bf16(pa, vb, oacc[th], 0, 0, 0);
        }
    }

    // store O fp32 [b][t][h]
    float* ob = out + (size_t)b * (T_ * H_);
#pragma unroll
    for (int th = 0; th < 4; ++th) {
        int h = 16 * th + lm;
#pragma unroll
        for (int r = 0; r < 4; ++r) {
            int m = 16 * tm + quad * 4 + r;
            ob[m * 64 + h] = oacc[th][r];
        }
    }
}

extern "C" void kernel_launch(void* const* d_in, const int* in_sizes, int n_in,
                              void* d_out, int out_size, void* d_ws, size_t ws_size,
                              hipStream_t stream) {
    const float* x  = (const float*)d_in[0];
    const float* Wq = (const float*)d_in[1];
    const float* Wk = (const float*)d_in[2];
    const float* Wv = (const float*)d_in[3];
    float* o = (float*)d_out;
    bf16* Wt = (bf16*)d_ws;   // needs 147456 bytes
    build_wt<<<dim3(36), dim3(256), 0, stream>>>(Wq, Wk, Wv, Wt);
    head_fused<<<dim3(B_), dim3(512), 0, stream>>>(x, Wt, o);
}